// Round 8
// baseline (31.554 us; speedup 1.0000x reference)
//
#include <hip/hip_runtime.h>

#define IMG_H 1024
#define IMG_W 1024
#define NIMG  16
#define NPIX  16777216.0f   // 16*1024*1024
#define SPI   128           // 8-row strips per image (1024/8)
#define NBLK  2048          // NIMG * SPI
#define LOG2E 1.44269504088896340736f
#define LN2   0.69314718055994530942f

// ws layout: one float4 per block: {bce, inter, sum_p, sum_t}. 2048*16B = 32 KB.

// __launch_bounds__(256, 3): 3 blocks/CU min -> VGPR cap ~168, so ALL 28
// float4 load destinations (112 VGPRs) can be live at once = one waitcnt
// per wave instead of ~5 serialized latency round-trips.
__global__ __launch_bounds__(256, 3) void dal_main(
    const float* __restrict__ xlogits,
    const float* __restrict__ gmask,
    const float* __restrict__ fuse,
    float4* __restrict__ ws4)
{
    const int bid  = blockIdx.x;
    const int img  = bid >> 7;          // / SPI
    const int q    = bid & 127;
    const int r0   = q << 3;            // rows r0 .. r0+7, r0 % 8 == 0
    const int tid  = (int)threadIdx.x;
    const int lane = tid & 63;
    const int j0   = tid * 4;           // 4 cols per thread

    const float w0 = fuse[0], w1 = fuse[1], w2 = fuse[2];

    const size_t ibase = (size_t)img * (IMG_H * IMG_W);
    const float* gi = gmask + ibase;
    const float* xi = xlogits + ibase;

    // Overlapping-load halo scheme: per row, float4 at j0-1 and j0+1 (clamped
    // at edges, fixed up with cndmask). Covers cols j0-1 .. j0+4.
    const int  jl   = (j0 > 0) ? (j0 - 1) : 0;
    const int  jr1  = (j0 + 4 < IMG_W) ? (j0 + 1) : (IMG_W - 4);
    const bool hasL = (j0 > 0);
    const bool hasR = (j0 + 4 < IMG_W);

    // ---- Phase 1: issue ALL 28 loads in one straight-line block (max MLP).
    // Mask rows first (consumed first), then logits (consumed last).
    float4 ga[10], gb[10];
    #pragma unroll
    for (int t = 0; t < 10; ++t) {
        int r  = r0 - 1 + t;
        int rc = r < 0 ? 0 : (r > IMG_H - 1 ? IMG_H - 1 : r);
        const float* row = gi + (size_t)rc * IMG_W;
        ga[t] = *reinterpret_cast<const float4*>(row + jl);
        gb[t] = *reinterpret_cast<const float4*>(row + jr1);
    }
    const float* xrow = xi + (size_t)r0 * IMG_W + j0;
    float4 xv[8];
    #pragma unroll
    for (int r = 0; r < 8; ++r)
        xv[r] = *reinterpret_cast<const float4*>(xrow + (size_t)r * IMG_W);

    // ---- Phase 2: rowmins over (j0+k-1 .. j0+k+1) + center values.
    float rm[10][4];
    float cv[8][4];
    #pragma unroll
    for (int t = 0; t < 10; ++t) {
        float c0 = hasL ? ga[t].x : 0.f;      // col j0-1 (0 at left edge)
        float c1 = hasL ? ga[t].y : ga[t].x;  // col j0
        float c2 = hasL ? ga[t].z : ga[t].y;  // col j0+1
        float c3 = hasL ? ga[t].w : ga[t].z;  // col j0+2
        float c4 = hasR ? gb[t].z : gb[t].w;  // col j0+3
        float c5 = hasR ? gb[t].w : 0.f;      // col j0+4 (0 at right edge)
        rm[t][0] = fminf(c0, fminf(c1, c2));
        rm[t][1] = fminf(c1, fminf(c2, c3));
        rm[t][2] = fminf(c2, fminf(c3, c4));
        rm[t][3] = fminf(c3, fminf(c4, c5));
        if (t >= 1 && t <= 8) {
            cv[t - 1][0] = c1; cv[t - 1][1] = c2;
            cv[t - 1][2] = c3; cv[t - 1][3] = c4;
        }
    }
    // Vertical zero-padding (block-uniform): rowmin of an all-zero pad row is 0.
    if (r0 == 0)          { rm[0][0] = rm[0][1] = rm[0][2] = rm[0][3] = 0.f; }
    if (r0 == IMG_H - 8)  { rm[9][0] = rm[9][1] = rm[9][2] = rm[9][3] = 0.f; }

    // bt (stride-1 boundary map): bt = (g == 1) && (min3x3 == 0)
    float bt[8][4];
    #pragma unroll
    for (int r = 0; r < 8; ++r)
        #pragma unroll
        for (int k = 0; k < 4; ++k) {
            float cm = fminf(rm[r][k], fminf(rm[r + 1][k], rm[r + 2][k]));
            bt[r][k] = (cv[r][k] > 0.5f && cm < 0.5f) ? 1.f : 0.f;
        }

    // bt4: rows r0..r0+3 -> bt(r0, j0); rows r0+4..r0+7 -> bt(r0+4, j0)
    // bt2: bt(r0+(r&~1), j0+(k&~1));  base2[rp][kp] = w1*bt2 + w2*bt4
    const float wb4A = w2 * bt[0][0];
    const float wb4B = w2 * bt[4][0];
    float base2[4][2];
    #pragma unroll
    for (int rp = 0; rp < 4; ++rp) {
        const float wb = (rp < 2) ? wb4A : wb4B;
        base2[rp][0] = fmaf(w1, bt[2 * rp][0], wb);
        base2[rp][1] = fmaf(w1, bt[2 * rp][2], wb);
    }

    // Per-pixel: f = w0*bt + base2;  t = f > 0.1
    // bce_px = ln2*log2(1+e^x) - x*t ; p = u/(1+u), u = e^x
    // sum_t via ballot+popcount (SALU). Dual accumulators (row parity) for ILP.
    float l2[2]  = {0.f, 0.f}, xt[2] = {0.f, 0.f};
    float itr[2] = {0.f, 0.f}, sp[2] = {0.f, 0.f};
    int st = 0;

    auto px = [&](float x, float btv, float b2v, int a) {
        float f = fmaf(w0, btv, b2v);
        bool  c = f > 0.1f;
        st += (int)__popcll(__ballot(c));
        float u   = __builtin_amdgcn_exp2f(x * LOG2E);   // e^x
        float opu = 1.f + u;
        float p   = u * __builtin_amdgcn_rcpf(opu);      // sigmoid(x)
        l2[a]  += __builtin_amdgcn_logf(opu);            // log2(1+e^x)
        sp[a]  += p;
        xt[a]  += c ? x : 0.f;
        itr[a] += c ? p : 0.f;
    };

    #pragma unroll
    for (int r = 0; r < 8; ++r) {
        const int   rp = r >> 1;
        const int   a  = r & 1;
        const float bA = base2[rp][0];
        const float bB = base2[rp][1];
        px(xv[r].x, bt[r][0], bA, a);
        px(xv[r].y, bt[r][1], bA, a);
        px(xv[r].z, bt[r][2], bB, a);
        px(xv[r].w, bt[r][3], bB, a);
    }

    float bce   = fmaf(LN2, l2[0] + l2[1], -(xt[0] + xt[1]));
    float inter = itr[0] + itr[1];
    float sump  = sp[0] + sp[1];

    // wave64 reduce (st is wave-uniform via ballot), cross-wave via LDS
    #pragma unroll
    for (int off = 32; off > 0; off >>= 1) {
        bce   += __shfl_down(bce, off);
        inter += __shfl_down(inter, off);
        sump  += __shfl_down(sump, off);
    }
    __shared__ float red[4][4];
    const int wid = tid >> 6;
    if (lane == 0) {
        red[0][wid] = bce; red[1][wid] = inter;
        red[2][wid] = sump; red[3][wid] = (float)st;
    }
    __syncthreads();
    if (tid == 0) {
        float4 o;
        o.x = red[0][0] + red[0][1] + red[0][2] + red[0][3];
        o.y = red[1][0] + red[1][1] + red[1][2] + red[1][3];
        o.z = red[2][0] + red[2][1] + red[2][2] + red[2][3];
        o.w = red[3][0] + red[3][1] + red[3][2] + red[3][3];
        ws4[bid] = o;
    }
}

// 1 block, 1024 threads. Thread t loads slots 2t, 2t+1 (same image: both in
// [128w, 128w+128) for wave w = t>>6). Wave-reduce, per-image dice, combine.
__global__ __launch_bounds__(1024) void dal_finalize(
    const float4* __restrict__ ws4, float* __restrict__ out)
{
    const int t    = (int)threadIdx.x;
    const int wv   = t >> 6;      // wave id == image id
    const int lane = t & 63;

    float4 a = ws4[2 * t];
    float4 b = ws4[2 * t + 1];
    float bce   = a.x + b.x;
    float inter = a.y + b.y;
    float sump  = a.z + b.z;
    float sumt  = a.w + b.w;

    #pragma unroll
    for (int off = 32; off > 0; off >>= 1) {
        bce   += __shfl_down(bce, off);
        inter += __shfl_down(inter, off);
        sump  += __shfl_down(sump, off);
        sumt  += __shfl_down(sumt, off);
    }

    __shared__ float sb[16], sd[16];
    if (lane == 0) {
        sb[wv] = bce;
        sd[wv] = 1.f - (2.f * inter + 1.f) / (sump + sumt + 1.f);
    }
    __syncthreads();
    if (t == 0) {
        float tb = 0.f, td = 0.f;
        #pragma unroll
        for (int i = 0; i < NIMG; ++i) { tb += sb[i]; td += sd[i]; }
        out[0] = tb / NPIX;
        out[1] = td / (float)NIMG;
    }
}

extern "C" void kernel_launch(void* const* d_in, const int* in_sizes, int n_in,
                              void* d_out, int out_size, void* d_ws, size_t ws_size,
                              hipStream_t stream)
{
    const float* x    = (const float*)d_in[0];  // boundary_logits [16,1,1024,1024]
    const float* g    = (const float*)d_in[1];  // gtmasks        [16,1024,1024]
    const float* fuse = (const float*)d_in[2];  // fuse_kernel    [3]
    float* out = (float*)d_out;
    float4* ws4 = (float4*)d_ws;

    dal_main<<<NBLK, 256, 0, stream>>>(x, g, fuse, ws4);
    dal_finalize<<<1, 1024, 0, stream>>>(ws4, out);
}